// Round 3
// baseline (112.659 us; speedup 1.0000x reference)
//
#include <hip/hip_runtime.h>
#include <hip/hip_bf16.h>
#include <hip/hip_cooperative_groups.h>

namespace cg = cooperative_groups;

#define N 512
#define D 256
#define MARGIN 0.1f
#define EPSF 1e-16f
#define PAD 4

__global__ __launch_bounds__(256) void fused_kernel(const float* __restrict__ E,
                                                    const int* __restrict__ labels,
                                                    float* __restrict__ pd,
                                                    float* __restrict__ bsum,
                                                    float* __restrict__ bcnt,
                                                    float* __restrict__ out) {
    __shared__ float As[32][D + PAD];
    __shared__ float Bs[32][D + PAD];
    __shared__ float norms[64];
    __shared__ int   lab[N];
    __shared__ float row[N];
    __shared__ unsigned long long masks[8];
    __shared__ short plist[N];
    __shared__ float ssum[256];
    __shared__ int   scnt[256];
    __shared__ double ds[256];
    __shared__ double dc[256];

    cg::grid_group grid = cg::this_grid();
    int t   = threadIdx.x;
    int blk = blockIdx.x;

    // ---------------- Phase 1: pd tile (32x32) + fused norms + label staging ----
    {
        int bi = blk >> 4, bj = blk & 15;

        lab[t]       = labels[t];
        lab[t + 256] = labels[t + 256];

        const float4* E4 = (const float4*)E;  // row = 64 float4
        #pragma unroll
        for (int it = 0; it < 8; ++it) {
            int idx = it * 256 + t;
            int r = idx >> 6;
            int c = idx & 63;
            float4 va = E4[(bi * 32 + r) * 64 + c];
            *(float4*)&As[r][c * 4] = va;
            float4 vb = E4[(bj * 32 + r) * 64 + c];
            *(float4*)&Bs[r][c * 4] = vb;
        }
        __syncthreads();

        // fused squared-norms: 4 threads per staged row
        {
            int r  = t >> 2;
            int ch = t & 3;
            const float* src = (r < 32) ? &As[r][0] : &Bs[r - 32][0];
            float np = 0.0f;
            #pragma unroll
            for (int d = 0; d < 64; d += 4) {
                float4 x = *(const float4*)&src[ch * 64 + d];
                np += x.x * x.x + x.y * x.y + x.z * x.z + x.w * x.w;
            }
            np += __shfl_xor(np, 1);
            np += __shfl_xor(np, 2);
            if (ch == 0) norms[r] = np;
        }
        __syncthreads();

        int ri = t >> 4;
        int cj = t & 15;
        float a00 = 0.f, a01 = 0.f, a10 = 0.f, a11 = 0.f;
        for (int d = 0; d < D; d += 4) {
            float4 x0 = *(const float4*)&As[ri][d];
            float4 x1 = *(const float4*)&As[ri + 16][d];
            float4 y0 = *(const float4*)&Bs[cj][d];
            float4 y1 = *(const float4*)&Bs[cj + 16][d];
            a00 += x0.x * y0.x + x0.y * y0.y + x0.z * y0.z + x0.w * y0.w;
            a01 += x0.x * y1.x + x0.y * y1.y + x0.z * y1.z + x0.w * y1.w;
            a10 += x1.x * y0.x + x1.y * y0.y + x1.z * y0.z + x1.w * y0.w;
            a11 += x1.x * y1.x + x1.y * y1.y + x1.z * y1.z + x1.w * y1.w;
        }

        int gi0 = bi * 32 + ri, gi1 = gi0 + 16;
        int gj0 = bj * 32 + cj, gj1 = gj0 + 16;
        float si0 = norms[ri],      si1 = norms[ri + 16];
        float sj0 = norms[32 + cj], sj1 = norms[32 + cj + 16];

        float d00 = fmaxf(si0 - 2.0f * a00 + sj0, 0.0f);
        float d01 = fmaxf(si0 - 2.0f * a01 + sj1, 0.0f);
        float d10 = fmaxf(si1 - 2.0f * a10 + sj0, 0.0f);
        float d11 = fmaxf(si1 - 2.0f * a11 + sj1, 0.0f);
        pd[gi0 * N + gj0] = (d00 > 0.0f) ? sqrtf(d00) : 0.0f;
        pd[gi0 * N + gj1] = (d01 > 0.0f) ? sqrtf(d01) : 0.0f;
        pd[gi1 * N + gj0] = (d10 > 0.0f) ? sqrtf(d10) : 0.0f;
        pd[gi1 * N + gj1] = (d11 > 0.0f) ? sqrtf(d11) : 0.0f;
    }

    __threadfence();
    grid.sync();

    // ---------------- Phase 2: two anchors per block -------------------------
    int wave = t >> 6;
    int lane = t & 63;
    unsigned long long lower = (1ULL << lane) - 1ULL;

    for (int a = 0; a < 2; ++a) {
        int i = blk + a * 256;

        row[t]       = pd[i * N + t];
        row[t + 256] = pd[i * N + t + 256];
        __syncthreads();

        int li = lab[i];
        int j1 = t, j2 = t + 256;
        bool p1 = (lab[j1] == li) && (j1 != i);
        bool p2 = (lab[j2] == li) && (j2 != i);
        unsigned long long m1 = __ballot(p1);
        unsigned long long m2 = __ballot(p2);
        if (lane == 0) { masks[wave] = m1; masks[wave + 4] = m2; }
        __syncthreads();

        int base1 = 0, base2 = 0, npos = 0;
        #pragma unroll
        for (int c = 0; c < 8; ++c) {
            int pc = __popcll(masks[c]);
            if (c < wave)     base1 += pc;
            if (c < wave + 4) base2 += pc;
            npos += pc;
        }
        if (p1) plist[base1 + __popcll(m1 & lower)] = (short)j1;
        if (p2) plist[base2 + __popcll(m2 & lower)] = (short)j2;
        __syncthreads();

        bool  n1  = (lab[j1] != li);
        bool  n2  = (lab[j2] != li);
        float dn1 = row[j1];
        float dn2 = row[j2];

        float sum = 0.0f;
        int cnt = 0;
        for (int p = 0; p < npos; ++p) {
            float dap = row[plist[p]];
            float v1 = dap - dn1 + MARGIN;
            float v2 = dap - dn2 + MARGIN;
            if (n1 && v1 > 0.0f) { sum += v1; cnt += (v1 > EPSF); }
            if (n2 && v2 > 0.0f) { sum += v2; cnt += (v2 > EPSF); }
        }

        ssum[t] = sum;
        scnt[t] = cnt;
        __syncthreads();
        #pragma unroll
        for (int s = 128; s > 0; s >>= 1) {
            if (t < s) {
                ssum[t] += ssum[t + s];
                scnt[t] += scnt[t + s];
            }
            __syncthreads();
        }
        if (t == 0) {
            bsum[i] = ssum[0];
            bcnt[i] = (float)scnt[0];
        }
        __syncthreads();
    }

    __threadfence();
    grid.sync();

    // ---------------- Phase 3: final reduce (block 0 only) -------------------
    if (blk == 0) {
        ds[t] = (double)bsum[t] + (double)bsum[t + 256];
        dc[t] = (double)bcnt[t] + (double)bcnt[t + 256];
        __syncthreads();
        #pragma unroll
        for (int st = 128; st > 0; st >>= 1) {
            if (t < st) {
                ds[t] += ds[t + st];
                dc[t] += dc[t + st];
            }
            __syncthreads();
        }
        if (t == 0) {
            double cnt = dc[0];
            out[0] = (float)(ds[0] / (cnt + 1e-16));
            out[1] = (float)cnt;
        }
    }
}

extern "C" void kernel_launch(void* const* d_in, const int* in_sizes, int n_in,
                              void* d_out, int out_size, void* d_ws, size_t ws_size,
                              hipStream_t stream) {
    const float* E      = (const float*)d_in[0];
    const int*   labels = (const int*)d_in[1];
    float*       out    = (float*)d_out;

    float* pd   = (float*)d_ws;          // 512*512
    float* bsum = pd + N * N;            // 512
    float* bcnt = bsum + 512;            // 512

    void* args[] = {(void*)&E, (void*)&labels, (void*)&pd,
                    (void*)&bsum, (void*)&bcnt, (void*)&out};
    hipLaunchCooperativeKernel((const void*)fused_kernel,
                               dim3(256), dim3(256), args, 0, stream);
}

// Round 4
// 29.435 us; speedup vs baseline: 3.8274x; 3.8274x over previous
//
#include <hip/hip_runtime.h>
#include <hip/hip_bf16.h>

#define N 512
#define D 256
#define MARGIN 0.1f
#define EPSF 1e-16f

// ---------------- Kernel 1: per-block pd-row compute + triplet accumulation ----
// Block b owns anchors i0=b, i1=b+256. Streams all of E (L2-resident) computing
// dot(E[i0],E[j]), dot(E[i1],E[j]), ||E[j]||^2 for all j, then runs the
// ballot-compacted triplet loop for both anchors. No pd materialization.
__global__ __launch_bounds__(256) void row_triplet_kernel(const float* __restrict__ E,
                                                          const int* __restrict__ labels,
                                                          float* __restrict__ bsum,
                                                          float* __restrict__ bcnt) {
    __shared__ float rowA[D];
    __shared__ float rowB[D];
    __shared__ float sqv[N];
    __shared__ float dr[2][N];
    __shared__ int   lab[N];
    __shared__ unsigned long long masks[8];
    __shared__ short plist[N];
    __shared__ float ssum[256];
    __shared__ int   scnt[256];

    int t   = threadIdx.x;
    int blk = blockIdx.x;
    int i0 = blk, i1 = blk + 256;

    const float4* E4 = (const float4*)E;   // each row = 64 float4

    // stage anchor rows (coalesced) + labels
    if (t < 64) {
        *(float4*)&rowA[t * 4] = E4[i0 * 64 + t];
    } else if (t < 128) {
        int c = t - 64;
        *(float4*)&rowB[c * 4] = E4[i1 * 64 + c];
    }
    lab[t]       = labels[t];
    lab[t + 256] = labels[t + 256];
    __syncthreads();

    // stream E: 4 lanes per j-row, 8 passes of 64 rows
    int rl = t >> 2;     // 0..63  (row within pass)
    int ch = t & 3;      // 0..3   (chunk lane)
    for (int p = 0; p < 8; ++p) {
        int j = p * 64 + rl;
        float dot0 = 0.f, dot1 = 0.f, sq = 0.f;
        #pragma unroll
        for (int k = 0; k < 16; ++k) {
            int c = ch + 4 * k;            // 4-lane groups read 64B contiguous
            float4 x  = E4[j * 64 + c];
            float4 va = *(const float4*)&rowA[c * 4];
            float4 vb = *(const float4*)&rowB[c * 4];
            dot0 += x.x * va.x + x.y * va.y + x.z * va.z + x.w * va.w;
            dot1 += x.x * vb.x + x.y * vb.y + x.z * vb.z + x.w * vb.w;
            sq   += x.x * x.x + x.y * x.y + x.z * x.z + x.w * x.w;
        }
        dot0 += __shfl_xor(dot0, 1);  dot0 += __shfl_xor(dot0, 2);
        dot1 += __shfl_xor(dot1, 1);  dot1 += __shfl_xor(dot1, 2);
        sq   += __shfl_xor(sq, 1);    sq   += __shfl_xor(sq, 2);
        if (ch == 0) {
            sqv[j]   = sq;
            dr[0][j] = dot0;
            dr[1][j] = dot1;
        }
    }
    __syncthreads();

    // raw dots -> distances (in place)
    float si0 = sqv[i0], si1 = sqv[i1];
    #pragma unroll
    for (int a = 0; a < 2; ++a) {
        int j = t + a * 256;
        float sj  = sqv[j];
        float dd0 = fmaxf(si0 - 2.0f * dr[0][j] + sj, 0.0f);
        float dd1 = fmaxf(si1 - 2.0f * dr[1][j] + sj, 0.0f);
        dr[0][j] = (dd0 > 0.0f) ? sqrtf(dd0) : 0.0f;
        dr[1][j] = (dd1 > 0.0f) ? sqrtf(dd1) : 0.0f;
    }
    __syncthreads();

    // triplet accumulation per anchor (ballot-compacted positive list)
    int wave = t >> 6;
    int lane = t & 63;
    unsigned long long lower = (1ULL << lane) - 1ULL;

    for (int a = 0; a < 2; ++a) {
        int i = (a == 0) ? i0 : i1;
        const float* row = dr[a];

        int li = lab[i];
        int j1 = t, j2 = t + 256;
        bool p1 = (lab[j1] == li) && (j1 != i);
        bool p2 = (lab[j2] == li) && (j2 != i);
        unsigned long long m1 = __ballot(p1);
        unsigned long long m2 = __ballot(p2);
        if (lane == 0) { masks[wave] = m1; masks[wave + 4] = m2; }
        __syncthreads();

        int base1 = 0, base2 = 0, npos = 0;
        #pragma unroll
        for (int c = 0; c < 8; ++c) {
            int pc = __popcll(masks[c]);
            if (c < wave)     base1 += pc;
            if (c < wave + 4) base2 += pc;
            npos += pc;
        }
        if (p1) plist[base1 + __popcll(m1 & lower)] = (short)j1;
        if (p2) plist[base2 + __popcll(m2 & lower)] = (short)j2;
        __syncthreads();

        bool  n1  = (lab[j1] != li);
        bool  n2  = (lab[j2] != li);
        float dn1 = row[j1];
        float dn2 = row[j2];

        float sum = 0.0f;
        int cnt = 0;
        for (int p = 0; p < npos; ++p) {
            float dap = row[plist[p]];
            float v1 = dap - dn1 + MARGIN;
            float v2 = dap - dn2 + MARGIN;
            if (n1 && v1 > 0.0f) { sum += v1; cnt += (v1 > EPSF); }
            if (n2 && v2 > 0.0f) { sum += v2; cnt += (v2 > EPSF); }
        }

        ssum[t] = sum;
        scnt[t] = cnt;
        __syncthreads();
        #pragma unroll
        for (int s = 128; s > 0; s >>= 1) {
            if (t < s) {
                ssum[t] += ssum[t + s];
                scnt[t] += scnt[t + s];
            }
            __syncthreads();
        }
        if (t == 0) {
            bsum[i] = ssum[0];
            bcnt[i] = (float)scnt[0];
        }
        __syncthreads();
    }
}

// ---------------- Kernel 2: final reduce (deterministic fixed order) ----------
__global__ __launch_bounds__(256) void final_kernel(const float* __restrict__ bsum,
                                                    const float* __restrict__ bcnt,
                                                    float* __restrict__ out) {
    __shared__ double s[256];
    __shared__ double c[256];
    int t = threadIdx.x;
    s[t] = (double)bsum[t] + (double)bsum[t + 256];
    c[t] = (double)bcnt[t] + (double)bcnt[t + 256];
    __syncthreads();
    #pragma unroll
    for (int st = 128; st > 0; st >>= 1) {
        if (t < st) {
            s[t] += s[t + st];
            c[t] += c[t + st];
        }
        __syncthreads();
    }
    if (t == 0) {
        double cnt = c[0];
        out[0] = (float)(s[0] / (cnt + 1e-16));
        out[1] = (float)cnt;
    }
}

extern "C" void kernel_launch(void* const* d_in, const int* in_sizes, int n_in,
                              void* d_out, int out_size, void* d_ws, size_t ws_size,
                              hipStream_t stream) {
    const float* E      = (const float*)d_in[0];
    const int*   labels = (const int*)d_in[1];
    float*       out    = (float*)d_out;

    float* bsum = (float*)d_ws;          // 512
    float* bcnt = bsum + 512;            // 512

    row_triplet_kernel<<<256, 256, 0, stream>>>(E, labels, bsum, bcnt);
    final_kernel<<<1, 256, 0, stream>>>(bsum, bcnt, out);
}